// Round 3
// baseline (375.083 us; speedup 1.0000x reference)
//
#include <hip/hip_runtime.h>
#include <stdint.h>

// GridManifoldNetwork, round 3.
// R2 result: level-split made tables L2-resident (FETCH 1.39GB -> 46MB).
// Remaining: (a) hash gathers cap at ~0.39 line/cyc/CU == ~64 outstanding
// L1 misses * 250cyc L2 latency -> bypass L1 with sc0 loads (SE scope);
// (b) dense_mlp DS-pipe-bound on per-point LDS weight reads -> 4 pts/thread.
//
// Levels: res=16,32,64,128,256,512; F=2; T=2^19; levels 3..5 hashed,
// size 2^19 -> & 0x7FFFF. Entry offsets: 0,4096,36864,299008,823296,1347584.

typedef float vfloat2 __attribute__((ext_vector_type(2)));

static __device__ __forceinline__ unsigned umin_(unsigned a, unsigned b) {
    return a < b ? a : b;
}

#define HP1 2654435761u
#define HP2 805459861u
#define HMASK ((1u << 19) - 1u)

// 8 divergent 8B gathers, L1-bypassed (sc0 => SE scope: serviced by L2,
// no CU-L1 allocation -> not limited by L1 outstanding-miss capacity).
static __device__ __forceinline__ void gather8_sc0(
    const float2* __restrict__ tab, const unsigned* __restrict__ idx,
    vfloat2* __restrict__ v)
{
    uint64_t a0 = (uint64_t)(tab + idx[0]);
    uint64_t a1 = (uint64_t)(tab + idx[1]);
    uint64_t a2 = (uint64_t)(tab + idx[2]);
    uint64_t a3 = (uint64_t)(tab + idx[3]);
    uint64_t a4 = (uint64_t)(tab + idx[4]);
    uint64_t a5 = (uint64_t)(tab + idx[5]);
    uint64_t a6 = (uint64_t)(tab + idx[6]);
    uint64_t a7 = (uint64_t)(tab + idx[7]);
    asm volatile(
        "global_load_dwordx2 %0, %8, off sc0\n\t"
        "global_load_dwordx2 %1, %9, off sc0\n\t"
        "global_load_dwordx2 %2, %10, off sc0\n\t"
        "global_load_dwordx2 %3, %11, off sc0\n\t"
        "global_load_dwordx2 %4, %12, off sc0\n\t"
        "global_load_dwordx2 %5, %13, off sc0\n\t"
        "global_load_dwordx2 %6, %14, off sc0\n\t"
        "global_load_dwordx2 %7, %15, off sc0\n\t"
        "s_waitcnt vmcnt(0)"
        : "=&v"(v[0]), "=&v"(v[1]), "=&v"(v[2]), "=&v"(v[3]),
          "=&v"(v[4]), "=&v"(v[5]), "=&v"(v[6]), "=&v"(v[7])
        : "v"(a0), "v"(a1), "v"(a2), "v"(a3),
          "v"(a4), "v"(a5), "v"(a6), "v"(a7));
}

// One hashed level: gather 8 corners from a single 4MB L2-resident table.
__global__ __launch_bounds__(256) void hash_level_kernel(
    const float* __restrict__ x,
    const float2* __restrict__ tab,
    float2* __restrict__ feat,
    float scale, int N)
{
    const int gid = blockIdx.x * 256 + threadIdx.x;
    if (gid >= N) return;

    const float px = __builtin_nontemporal_load(x + 3 * gid + 0);
    const float py = __builtin_nontemporal_load(x + 3 * gid + 1);
    const float pz = __builtin_nontemporal_load(x + 3 * gid + 2);

    const float p0 = fmaf((px + 1.0f) * 0.5f, scale, 0.5f);
    const float p1 = fmaf((py + 1.0f) * 0.5f, scale, 0.5f);
    const float p2 = fmaf((pz + 1.0f) * 0.5f, scale, 0.5f);
    const float g0 = floorf(p0), g1 = floorf(p1), g2 = floorf(p2);
    const float f0 = p0 - g0, f1 = p1 - g1, f2 = p2 - g2;
    const unsigned i0 = (unsigned)g0, i1 = (unsigned)g1, i2 = (unsigned)g2;

    const float wx[2] = {1.0f - f0, f0};
    const float wy[2] = {1.0f - f1, f1};
    const float wz[2] = {1.0f - f2, f2};
    const unsigned hx[2] = {i0, i0 + 1u};
    const unsigned hy[2] = {i1 * HP1, (i1 + 1u) * HP1};
    const unsigned hz[2] = {i2 * HP2, (i2 + 1u) * HP2};

    unsigned idx[8];
    float w[8];
    #pragma unroll
    for (int c = 0; c < 8; ++c) {
        const int bx = c & 1, by = (c >> 1) & 1, bz = (c >> 2) & 1;
        idx[c] = (hx[bx] ^ hy[by] ^ hz[bz]) & HMASK;
        w[c] = wx[bx] * wy[by] * wz[bz];
    }
    vfloat2 v[8];
    gather8_sc0(tab, idx, v);

    float a0 = 0.0f, a1 = 0.0f;
    #pragma unroll
    for (int c = 0; c < 8; ++c) {
        a0 = fmaf(w[c], v[c].x, a0);
        a1 = fmaf(w[c], v[c].y, a1);
    }
    float* fp = (float*)(feat + gid);
    __builtin_nontemporal_store(a0, fp + 0);
    __builtin_nontemporal_store(a1, fp + 1);
}

// Dense levels 0..2 + MLP(15->64->1), 4 points per thread so each LDS
// weight read is amortized 4x (R2 was DS-pipe bound).
__global__ __launch_bounds__(256) void dense_mlp_kernel(
    const float* __restrict__ x,
    const float* __restrict__ grid,
    const float2* __restrict__ feat,   // [3][N]: levels 3,4,5
    const float* __restrict__ W0,
    const float* __restrict__ b0,
    const float* __restrict__ W1,
    const float* __restrict__ b1,
    float* __restrict__ out, int N)
{
    __shared__ float sW0T[64 * 16];   // sW0T[j][i] = W0[i*64+j], b0 in i=15
    __shared__ float sW1[64];

    const int tid = threadIdx.x;
    for (int t = tid; t < 960; t += 256) {
        int j = t / 15;
        int i = t - j * 15;
        sW0T[j * 16 + i] = W0[i * 64 + j];
    }
    if (tid < 64) {
        sW0T[tid * 16 + 15] = b0[tid];
        sW1[tid] = W1[tid];
    }
    __syncthreads();

    const int base = blockIdx.x * 1024 + tid;
    const float2* gtab = (const float2*)grid;

    float h[4][16];

    #pragma unroll
    for (int k = 0; k < 4; ++k) {
        const int g = base + 256 * k;
        const int gs = (g < N) ? g : 0;

        const float px = __builtin_nontemporal_load(x + 3 * gs + 0);
        const float py = __builtin_nontemporal_load(x + 3 * gs + 1);
        const float pz = __builtin_nontemporal_load(x + 3 * gs + 2);
        const float xn0 = (px + 1.0f) * 0.5f;
        const float xn1 = (py + 1.0f) * 0.5f;
        const float xn2 = (pz + 1.0f) * 0.5f;

        h[k][0] = px; h[k][1] = py; h[k][2] = pz;
        h[k][15] = 1.0f;

        // Levels 0,1 (32KB + 256KB tables): normal loads, L1-friendly.
        constexpr int      RES01[2] = {16, 32};
        constexpr unsigned OFF01[2] = {0u, 4096u};
        #pragma unroll
        for (int l = 0; l < 2; ++l) {
            const float scale = (float)(RES01[l] - 1);
            const float p0 = fmaf(xn0, scale, 0.5f);
            const float p1 = fmaf(xn1, scale, 0.5f);
            const float p2 = fmaf(xn2, scale, 0.5f);
            const float g0 = floorf(p0), g1 = floorf(p1), g2 = floorf(p2);
            const float f0 = p0 - g0, f1 = p1 - g1, f2 = p2 - g2;
            const unsigned i0 = (unsigned)g0, i1 = (unsigned)g1, i2 = (unsigned)g2;

            const float wx[2] = {1.0f - f0, f0};
            const float wy[2] = {1.0f - f1, f1};
            const float wz[2] = {1.0f - f2, f2};
            const unsigned rm1 = (unsigned)(RES01[l] - 1);
            const unsigned res = (unsigned)RES01[l];
            const unsigned cx[2] = {umin_(i0, rm1), umin_(i0 + 1u, rm1)};
            const unsigned cy[2] = {umin_(i1, rm1) * res, umin_(i1 + 1u, rm1) * res};
            const unsigned cz[2] = {umin_(i2, rm1) * res * res,
                                    umin_(i2 + 1u, rm1) * res * res};
            float a0 = 0.0f, a1 = 0.0f;
            #pragma unroll
            for (int c = 0; c < 8; ++c) {
                const int bx = c & 1, by = (c >> 1) & 1, bz = (c >> 2) & 1;
                const unsigned idx = cx[bx] + cy[by] + cz[bz];
                const float ww = wx[bx] * wy[by] * wz[bz];
                const float2 v = gtab[OFF01[l] + idx];
                a0 = fmaf(ww, v.x, a0);
                a1 = fmaf(ww, v.y, a1);
            }
            h[k][3 + 2 * l] = a0;
            h[k][4 + 2 * l] = a1;
        }

        // Level 2 (2MB table): random in L2, bypass L1.
        {
            const float p0 = fmaf(xn0, 63.0f, 0.5f);
            const float p1 = fmaf(xn1, 63.0f, 0.5f);
            const float p2 = fmaf(xn2, 63.0f, 0.5f);
            const float g0 = floorf(p0), g1 = floorf(p1), g2 = floorf(p2);
            const float f0 = p0 - g0, f1 = p1 - g1, f2 = p2 - g2;
            const unsigned i0 = (unsigned)g0, i1 = (unsigned)g1, i2 = (unsigned)g2;

            const float wx[2] = {1.0f - f0, f0};
            const float wy[2] = {1.0f - f1, f1};
            const float wz[2] = {1.0f - f2, f2};
            const unsigned cx[2] = {umin_(i0, 63u), umin_(i0 + 1u, 63u)};
            const unsigned cy[2] = {umin_(i1, 63u) * 64u, umin_(i1 + 1u, 63u) * 64u};
            const unsigned cz[2] = {umin_(i2, 63u) * 4096u, umin_(i2 + 1u, 63u) * 4096u};

            unsigned idx[8];
            float w[8];
            #pragma unroll
            for (int c = 0; c < 8; ++c) {
                const int bx = c & 1, by = (c >> 1) & 1, bz = (c >> 2) & 1;
                idx[c] = cx[bx] + cy[by] + cz[bz];
                w[c] = wx[bx] * wy[by] * wz[bz];
            }
            vfloat2 v[8];
            gather8_sc0(gtab + 36864u, idx, v);
            float a0 = 0.0f, a1 = 0.0f;
            #pragma unroll
            for (int c = 0; c < 8; ++c) {
                a0 = fmaf(w[c], v[c].x, a0);
                a1 = fmaf(w[c], v[c].y, a1);
            }
            h[k][7] = a0;
            h[k][8] = a1;
        }

        // Hashed-level partial features from d_ws.
        #pragma unroll
        for (int l = 0; l < 3; ++l) {
            const float* fp = (const float*)(feat + (size_t)l * N + gs);
            h[k][9 + 2 * l]  = __builtin_nontemporal_load(fp + 0);
            h[k][10 + 2 * l] = __builtin_nontemporal_load(fp + 1);
        }
    }

    // MLP: out = relu(h @ W0 + b0) @ W1 + b1 for 4 points; weights read
    // once per j from LDS (ds_read_b128 x4), reused across 4 points.
    const float b1v = b1[0];
    float o[4] = {b1v, b1v, b1v, b1v};

    #pragma unroll 2
    for (int j = 0; j < 64; ++j) {
        float4 wv[4];
        const float4* wrow = (const float4*)(sW0T + j * 16);
        wv[0] = wrow[0]; wv[1] = wrow[1]; wv[2] = wrow[2]; wv[3] = wrow[3];
        const float* wf = (const float*)wv;
        const float w1j = sW1[j];
        #pragma unroll
        for (int k = 0; k < 4; ++k) {
            float s = 0.0f;
            #pragma unroll
            for (int i = 0; i < 16; ++i)
                s = fmaf(h[k][i], wf[i], s);
            s = fmaxf(s, 0.0f);
            o[k] = fmaf(s, w1j, o[k]);
        }
    }

    #pragma unroll
    for (int k = 0; k < 4; ++k) {
        const int g = base + 256 * k;
        if (g < N) __builtin_nontemporal_store(o[k], out + g);
    }
}

extern "C" void kernel_launch(void* const* d_in, const int* in_sizes, int n_in,
                              void* d_out, int out_size, void* d_ws, size_t ws_size,
                              hipStream_t stream) {
    const float* x    = (const float*)d_in[0];
    const float* grid = (const float*)d_in[1];
    const float* W0   = (const float*)d_in[2];
    const float* b0   = (const float*)d_in[3];
    const float* W1   = (const float*)d_in[4];
    const float* b1   = (const float*)d_in[5];
    float* out = (float*)d_out;

    const int N = in_sizes[0] / 3;
    const int blocks1 = (N + 255) / 256;
    const int blocks4 = (N + 1023) / 1024;

    const float2* gtab = (const float2*)grid;
    float2* feat = (float2*)d_ws;               // [3][N] float2 = 48MB

    hash_level_kernel<<<blocks1, 256, 0, stream>>>(x, gtab + 299008u,
                                                   feat + (size_t)0 * N, 127.0f, N);
    hash_level_kernel<<<blocks1, 256, 0, stream>>>(x, gtab + 823296u,
                                                   feat + (size_t)1 * N, 255.0f, N);
    hash_level_kernel<<<blocks1, 256, 0, stream>>>(x, gtab + 1347584u,
                                                   feat + (size_t)2 * N, 511.0f, N);
    dense_mlp_kernel<<<blocks4, 256, 0, stream>>>(x, grid, feat, W0, b0, W1, b1,
                                                  out, N);
}